// Round 13
// baseline (992.499 us; speedup 1.0000x reference)
//
#include <hip/hip_runtime.h>
#include <cfloat>
#include <math.h>

#define NOBS   256
#define NY     50
#define NX     30
#define NITER  400
#define LRATE  0.05f
#define CSTR   260     // ep_t column stride (floats); %4==0 keeps float4 LDS loads 16B-aligned
#define THRANK 28      // theta tracks the rank-28 KEY -> C = 29 every valid iter (stable)
#define CAND   32      // candidate capacity: window [ceil(a256), 32], a256<=25.6 -> >=3 slack

typedef float f32x2 __attribute__((ext_vector_type(2)));

__device__ __forceinline__ float rl_f(float x, int k) {
  return __int_as_float(__builtin_amdgcn_readlane(__float_as_int(x), k));
}
__device__ __forceinline__ int rl_i(int x, int k) {
  return __builtin_amdgcn_readlane(x, k);
}

// wave64 max: row_shr 1,2,4,8 + row_bcast 15,31; old=x keeps unwritten lanes at identity.
#define DPP_MAXSTEP(x, ctrl)                                                       \
  x = fmaxf(x, __int_as_float(__builtin_amdgcn_update_dpp(                         \
        __float_as_int(x), __float_as_int(x), (ctrl), 0xF, 0xF, false)))

// wave64 SUM step: old=0 (NOT old=x -- sum is not idempotent; unfilled lanes must add 0).
#define DPP_SUMSTEP(x, ctrl, rmask)                                                \
  x += __int_as_float(__builtin_amdgcn_update_dpp(                                 \
        0, __float_as_int(x), (ctrl), (rmask), 0xF, false))

__device__ __forceinline__ float wave_sum_bcast(float x) {
  // full 64-lane sum, result broadcast to all lanes (readlane 63)
  DPP_SUMSTEP(x, 0x111, 0xF);   // row_shr:1
  DPP_SUMSTEP(x, 0x112, 0xF);   // row_shr:2
  DPP_SUMSTEP(x, 0x114, 0xF);   // row_shr:4
  DPP_SUMSTEP(x, 0x118, 0xF);   // row_shr:8  -> lanes 15/31/47/63 hold row sums
  DPP_SUMSTEP(x, 0x142, 0xA);   // row_bcast:15, rows 1,3 -> lanes 31/63 accumulate
  DPP_SUMSTEP(x, 0x143, 0xC);   // row_bcast:31, rows 2,3 -> lane 63 = total
  return rl_f(x, 63);
}

// R13 = R12 (778us) + gradient reduction via LDS ds_add_f32 atomics.
// Calibration from R9->R12 (-365cyc for 4 loads+16 ops): DS-pipe occupancy x lockstep chain
// is the binding resource (~46 DS ops/wave/iter, ~1500 of 4670 cyc). The rdx exchange
// (1 write + 8 reads/thread) is the largest removable DS block -> replace with ONE
// atomicAdd(&s4buf[pp][lane]) + ONE b32 read (parity buffers, wave-7 zeroes the other --
// the exact scheme R2 validated). -7 DS ops/wave, post-B2 chain 8 reads+tree -> 1 read.
// s4 rounding becomes order-nondeterministic (R2 precedent: passed). Else identical to R12.
__global__ __launch_bounds__(512) __attribute__((amdgpu_waves_per_eu(2, 2)))
void dro_kernel(
    const float* __restrict__ X, const float* __restrict__ Y,
    const float* __restrict__ W, const float* __restrict__ Bb,
    const float* __restrict__ DLT, const float* __restrict__ GMM,
    float* __restrict__ out)
{
  __shared__ __align__(16) float smem[51 * CSTR];   // init: ep_t; after: overlays below
  __shared__ __align__(16) unsigned rrk[NOBS];      // full u32 keys (fallback scan)
  __shared__ __align__(16) unsigned ckey[2][128];   // parity-buffered dense candidates
  __shared__ __align__(16) float s4buf[2][64];      // parity-buffered gradient sums (atomic)
  __shared__ __align__(16) float wmax4[4];
  __shared__ __align__(16) int   wtie4[4];
  __shared__ int cctr[2];                           // parity-buffered candidate counter
  __shared__ unsigned th_key;

  // Overlays (valid once ep_t is dead; disjoint; zs/cfs are WAVE-PRIVATE):
  float* const zs  = smem;                   // [8][64] replicated z per wave
  float* const cfs = smem + 512;             // [8][64] coef transpose (wave-private)

  const int tid  = threadIdx.x;     // 0..511
  const int oid  = tid & 255;       // owned observation
  const int half = tid >> 8;        // bwd obs-slice half; A(0) writes shared state
  const int lane = tid & 63;
  const int w8   = tid >> 6;        // wave 0..7
  const int wsc  = w8 & 3;          // obs quarter (obs base wsc*64)
  const int t    = blockIdx.x;      // scenario

  const float delta = DLT[0];
  const float gamma = GMM[0];
  const float a     = fminf(delta * 0.5f, 255.0f / 256.0f);
  const float a256  = a * 256.0f;

  // ---- init: FULL residual row of owned obs (packed pairs); stage ep column-major (A) ----
  f32x2 er2[25];                                 // er2[p] = {er[2p], er[2p+1]}
  {
    float xr[NX];
    #pragma unroll
    for (int k = 0; k < NX; ++k) xr[k] = X[oid * NX + k];
    #pragma unroll
    for (int j = 0; j < NY; ++j) {               // W/B wave-uniform -> scalar loads
      float acc = Bb[j];
      #pragma unroll
      for (int k = 0; k < NX; ++k) acc = fmaf(xr[k], W[j * NX + k], acc);
      const float e = Y[oid * NY + j] - acc;
      if (j & 1) er2[j >> 1].y = e; else er2[j >> 1].x = e;   // static (unrolled)
      if (half == 0) smem[j * CSTR + oid] = e;
    }
    if (half == 0) smem[NY * CSTR + oid] = 1.0f; // ones column -> c gradient
  }
  float yhl;                                     // y_hat[t][lane] per-lane copy
  {
    const int jr = (lane < NY) ? lane : 0;
    float acc = Bb[jr];
    #pragma unroll
    for (int k = 0; k < NX; ++k) acc = fmaf(X[t * NX + k], W[jr * NX + k], acc);
    yhl = acc;
    if (tid < NY) out[NOBS * NY + t * NY + tid] = acc;
  }
  if (tid == 0) { th_key = 0xFFFFFFFFu; cctr[0] = 0; cctr[1] = 0; }
  if (tid < CAND) { ckey[0][tid] = 0xFFFFFFFFu; ckey[1][tid] = 0xFFFFFFFFu; }
  if (tid < 128) ((float*)s4buf)[tid] = 0.0f;    // zero both parity buffers
  __syncthreads();

  // epb: iteration-invariant backward slice (packed pairs). Lane l: col min(l,50),
  // obs [wsc*64 + half*32, +32). coef of those obs -> cfs[w8*64 + half*32 + q].
  f32x2 epb2[16];
  {
    const int colc = (lane < 51) ? lane : 50;
    const float* eb = &smem[colc * CSTR + wsc * 64 + half * 32];
    #pragma unroll
    for (int q = 0; q < 8; ++q) {
      const float4 e4 = *(const float4*)&eb[4 * q];
      epb2[2*q]   = (f32x2){e4.x, e4.y};
      epb2[2*q+1] = (f32x2){e4.z, e4.w};
    }
  }
  __syncthreads();                               // ep_t dead -> overlays may be written

  float zv = (lane < NY) ? (1.0f / NY) : 0.0f;   // z one entry/lane, replicated per wave
  float cc = 0.0f;                               // c, replicated (bitwise identical)
  unsigned thk = 0xFFFFFFFFu;                    // loop-carried th_key copy (== LDS value)
  zs[w8 * 64 + lane] = zv;                       // wave-private z buffer (lanes>=50 -> 0)

  #pragma unroll 1
  for (int it = 0; it < NITER; ++it) {
    const int pp = it & 1;

    // ---- P0: fwd dot via wave-private LDS broadcast; packed FMA (25 pk ops) ----
    const float4* zp = (const float4*)&zs[w8 * 64];
    f32x2 a01 = {0.f, 0.f}, a23 = {0.f, 0.f};
    #pragma unroll
    for (int jq = 0; jq < 12; ++jq) {
      const float4 z4 = zp[jq];
      a01 = __builtin_elementwise_fma(er2[2*jq],   (f32x2){z4.x, z4.y}, a01);
      a23 = __builtin_elementwise_fma(er2[2*jq+1], (f32x2){z4.z, z4.w}, a23);
    }
    {
      const float4 z4 = zp[12];                  // z[48],z[49],0,0
      a01 = __builtin_elementwise_fma(er2[24], (f32x2){z4.x, z4.y}, a01);
    }
    const float u = ((a01.x + a23.x) + (a01.y + a23.y)) - cc;
    const float r = u * u;
    const unsigned key = __float_as_uint(r);     // non-negative f32 bits sort as u32

    float m = r;
    DPP_MAXSTEP(m, 0x111); DPP_MAXSTEP(m, 0x112);
    DPP_MAXSTEP(m, 0x114); DPP_MAXSTEP(m, 0x118);
    DPP_MAXSTEP(m, 0x142); DPP_MAXSTEP(m, 0x143);
    const float mw = rl_f(m, 63);                // wave (=quarter) max
    const int   wt = __popcll(__ballot(r == mw));

    const bool cond = (key <= thk);
    if (half == 0) {                             // A writes all shared state
      rrk[oid] = key;
      const unsigned long long cmask = __ballot(cond);
      const int cpos = __popcll(cmask & ((1ull << lane) - 1ull));
      const int cq   = __popcll(cmask);
      int base = 0;
      if (lane == 0) base = atomicAdd(&cctr[pp], cq);   // dense cross-quarter offset
      base = rl_i(base, 0);
      const int pos = base + cpos;               // slot order nondeterministic; cnt is
      if (cond && pos < 128) ckey[pp][pos] = key;//   order-independent -> deterministic
      if (lane == 0) { wmax4[wsc] = mw; wtie4[wsc] = wt; }
    }
    __syncthreads();                             // B1: ckey/cctr/stats/rrk

    // ---- P1: local rank scan (broadcast LDS loads); coef; bwd partials ----
    const int Cu = __builtin_amdgcn_readfirstlane(cctr[pp]);
    if (tid == 0) cctr[pp ^ 1] = 0;              // consumed last iter; next write 2 bar. away
    if (tid < CAND) ckey[pp ^ 1][tid] = 0xFFFFFFFFu;    // sentinel prefill for next iter

    const float4 wm  = *(const float4*)wmax4;
    const int4   wtv = *(const int4*)wtie4;
    const float mx = fmaxf(fmaxf(wm.x, wm.y), fmaxf(wm.z, wm.w));
    const int   cm = (wm.x == mx ? wtv.x : 0) + (wm.y == mx ? wtv.y : 0)
                   + (wm.z == mx ? wtv.z : 0) + (wm.w == mx ? wtv.w : 0);
    const bool ismax = (r == mx);
    const bool valid = ((float)Cu >= a256) && (Cu <= CAND);

    int cnt;
    if (__builtin_expect(valid, 1)) {
      // candidates (keys<=thk) downward-closed -> candidate rank == exact global rank;
      // non-candidates get cnt=C>=a256 -> gfac=1/256 (exact). Sentinels never count.
      const uint4* cp = (const uint4*)&ckey[pp][0];     // uniform addr -> broadcast reads
      int n0 = 0, n1 = 0, n2 = 0, n3 = 0;
      #pragma unroll
      for (int jq = 0; jq < CAND / 4; ++jq) {
        const uint4 k4 = cp[jq];
        n0 += (k4.x < key) ? 1 : 0;
        n1 += (k4.y < key) ? 1 : 0;
        n2 += (k4.z < key) ? 1 : 0;
        n3 += (k4.w < key) ? 1 : 0;
      }
      cnt = (n0 + n1) + (n2 + n3);
    } else {                                     // iter 0 / drift: exact full scan
      const uint4* p = (const uint4*)rrk;
      int n0 = 0, n1 = 0, n2 = 0, n3 = 0;
      #pragma unroll 4
      for (int jq = 0; jq < 64; ++jq) {
        const uint4 k4 = p[jq];
        n0 += (k4.x < key) ? 1 : 0;
        n1 += (k4.y < key) ? 1 : 0;
        n2 += (k4.z < key) ? 1 : 0;
        n3 += (k4.w < key) ? 1 : 0;
      }
      cnt = (n0 + n1) + (n2 + n3);
    }
    // rank-THRANK key refresh (unique when valid; dup writes of same value benign)
    if (cnt == THRANK && (!valid || cond)) th_key = key;

    const float gfac  = fminf(fmaxf((float)cnt + 1.0f - a256, 0.0f), 1.0f) * (1.0f / 256.0f);
    const float g     = gfac + (ismax ? (a / (float)cm) : 0.0f);
    const float coefv = 2.0f * u * g;

    // backward: coef transpose via wave-private LDS; packed FMA (16 pk ops);
    // gradient reduction via LDS atomic add (8 wave-partials -> s4buf[pp][lane])
    cfs[w8 * 64 + lane] = coefv;                 // in-order DS: reads below see this
    const float4* cfp = (const float4*)&cfs[w8 * 64 + half * 32];
    f32x2 qa = {0.f, 0.f}, qb = {0.f, 0.f};
    #pragma unroll
    for (int q = 0; q < 8; ++q) {
      const float4 c4 = cfp[q];                  // coef of obs wsc*64 + half*32 + 4q..+3
      qa = __builtin_elementwise_fma((f32x2){c4.x, c4.y}, epb2[2*q],   qa);
      qb = __builtin_elementwise_fma((f32x2){c4.z, c4.w}, epb2[2*q+1], qb);
    }
    atomicAdd(&s4buf[pp][lane], (qa.x + qb.x) + (qa.y + qb.y));  // lanes>=51: unused slots
    __syncthreads();                             // B2: s4buf[pp] + th_key
    thk = th_key;                                // prefetch: final since P1; next write is
                                                 //   after next B1 -> WAR-safe
    // ---- P2: z/c gradient step; warm-started Michelot projection (0 LDS) ----
    const float s4 = s4buf[pp][lane];            // single b32, stride-1, conflict-free
    if (w8 == 7) s4buf[pp ^ 1][lane] = 0.0f;     // zero next parity buffer; last read was
                                                 //   P2(it-1), >=2 barriers ago; next atomics
                                                 //   P1(it+1), fenced by B1(it+1)
    cc = cc + LRATE * rl_f(s4, NY);              // gc = -sum(coef); lane 50 = ones column
    const float gz = s4 - gamma * yhl;
    const float v  = zv - LRATE * gz;            // column form: lane j holds v_j

    // Warm-start: seed support with carried {zv>0}; ballot-equality convergence is exact
    // (any fixed point (tau, A={v>tau}) with tau=(S_A-1)/|A| IS the projection).
    float tau = 0.0f;
    {
      bool cur = (lane < NY) && (zv > 0.0f);     // nonempty: sum(z)=1
      unsigned long long bal = __ballot(cur);
      int   n = __popcll(bal);
      float S = wave_sum_bcast(cur ? v : 0.0f);
      bool done = false;
      #pragma unroll 1
      for (int pass = 0; pass < 8; ++pass) {
        tau = (S - 1.0f) * __builtin_amdgcn_rcpf((float)n);
        const bool nxt = (lane < NY) && (v > tau);
        const unsigned long long nbal = __ballot(nxt);   // nonempty: max>mean>tau
        if (nbal == bal) { done = true; break; } // set equality -> fixed point (uniform)
        bal = nbal;
        n   = __popcll(nbal);
        S   = wave_sum_bcast(nxt ? v : 0.0f);
      }
      if (__builtin_expect(!done, 0)) {          // fallback: monotone shrink-from-full
        bool inm = (lane < NY);
        float Sf = wave_sum_bcast(inm ? v : 0.0f);
        int   nf = NY;
        #pragma unroll 1
        for (int pass = 0; pass < 32; ++pass) {
          tau = (Sf - 1.0f) * __builtin_amdgcn_rcpf((float)nf);
          const bool nin = inm && (v > tau);
          const int  nn  = __popcll(__ballot(nin));
          if (nn == nf) break;
          Sf = wave_sum_bcast(nin ? v : 0.0f);
          nf = nn;
          inm = nin;
        }
      }
    }
    zv = (lane < NY) ? fmaxf(v - tau, 0.0f) : 0.0f;
    zs[w8 * 64 + lane] = zv;                     // wave-private; next-iter P0 reads (in-order)
  }

  if (w8 == 0 && lane < NY) out[t * NY + lane] = zv;

}

extern "C" void kernel_launch(void* const* d_in, const int* in_sizes, int n_in,
                              void* d_out, int out_size, void* d_ws, size_t ws_size,
                              hipStream_t stream) {
  (void)in_sizes; (void)n_in; (void)d_ws; (void)ws_size; (void)out_size;
  const float* X   = (const float*)d_in[0];
  const float* Y   = (const float*)d_in[1];
  const float* W   = (const float*)d_in[2];
  const float* B   = (const float*)d_in[3];
  const float* DLT = (const float*)d_in[4];
  const float* GMM = (const float*)d_in[5];
  float* out = (float*)d_out;
  hipLaunchKernelGGL(dro_kernel, dim3(NOBS), dim3(512), 0, stream,
                     X, Y, W, B, DLT, GMM, out);
}

// Round 14
// 778.849 us; speedup vs baseline: 1.2743x; 1.2743x over previous
//
#include <hip/hip_runtime.h>
#include <cfloat>
#include <math.h>

#define NOBS   256
#define NY     50
#define NX     30
#define NITER  400
#define LRATE  0.05f
#define CSTR   260     // ep_t column stride (floats); %4==0 keeps float4 LDS loads 16B-aligned
#define THRANK 28      // theta tracks the rank-28 KEY -> C = 29 every valid iter (stable)
#define CAND   32      // candidate capacity: window [ceil(a256), 32], a256<=25.6 -> >=3 slack

typedef float f32x2 __attribute__((ext_vector_type(2)));

__device__ __forceinline__ float rl_f(float x, int k) {
  return __int_as_float(__builtin_amdgcn_readlane(__float_as_int(x), k));
}
__device__ __forceinline__ int rl_i(int x, int k) {
  return __builtin_amdgcn_readlane(x, k);
}

// wave64 max: row_shr 1,2,4,8 + row_bcast 15,31; old=x keeps unwritten lanes at identity.
#define DPP_MAXSTEP(x, ctrl)                                                       \
  x = fmaxf(x, __int_as_float(__builtin_amdgcn_update_dpp(                         \
        __float_as_int(x), __float_as_int(x), (ctrl), 0xF, 0xF, false)))

// wave64 SUM step: old=0 (NOT old=x -- sum is not idempotent; unfilled lanes must add 0).
#define DPP_SUMSTEP(x, ctrl, rmask)                                                \
  x += __int_as_float(__builtin_amdgcn_update_dpp(                                 \
        0, __float_as_int(x), (ctrl), (rmask), 0xF, false))

__device__ __forceinline__ float wave_sum_bcast(float x) {
  // full 64-lane sum, result broadcast to all lanes (readlane 63)
  DPP_SUMSTEP(x, 0x111, 0xF);   // row_shr:1
  DPP_SUMSTEP(x, 0x112, 0xF);   // row_shr:2
  DPP_SUMSTEP(x, 0x114, 0xF);   // row_shr:4
  DPP_SUMSTEP(x, 0x118, 0xF);   // row_shr:8  -> lanes 15/31/47/63 hold row sums
  DPP_SUMSTEP(x, 0x142, 0xA);   // row_bcast:15, rows 1,3 -> lanes 31/63 accumulate
  DPP_SUMSTEP(x, 0x143, 0xC);   // row_bcast:31, rows 2,3 -> lane 63 = total
  return rl_f(x, 63);
}

// R14 = R12 verbatim (778us, session best; R13's contended-LDS-atomic gradient reduction
// regressed to 992 -- ds_add_f32 with 8-wave same-address contention costs ~65cyc/op,
// ~15x a plain DS op; reverted).
// Kernel is latency/sync-bound, NOT roofline-bound (HBM 0.01%, VALU 44%, DS ~30%):
// 2 irreducible cross-wave exchanges + ~1100cyc dependent chain per PGD iter x 400 iters.
// Tested-and-rejected: more TLP (R10 spill + lockstep math), fewer waves (R6), scan
// deletion via exact threshold (R11 -- slack is mandatory), LDS atomics (R13).
__global__ __launch_bounds__(512) __attribute__((amdgpu_waves_per_eu(2, 2)))
void dro_kernel(
    const float* __restrict__ X, const float* __restrict__ Y,
    const float* __restrict__ W, const float* __restrict__ Bb,
    const float* __restrict__ DLT, const float* __restrict__ GMM,
    float* __restrict__ out)
{
  __shared__ __align__(16) float smem[51 * CSTR];   // init: ep_t; after: overlays below
  __shared__ __align__(16) unsigned rrk[NOBS];      // full u32 keys (fallback scan)
  __shared__ __align__(16) unsigned ckey[2][128];   // parity-buffered dense candidates
  __shared__ __align__(16) float wmax4[4];
  __shared__ __align__(16) int   wtie4[4];
  __shared__ int cctr[2];                           // parity-buffered candidate counter
  __shared__ unsigned th_key;

  // Overlays (valid once ep_t is dead; disjoint; zs/cfs are WAVE-PRIVATE):
  float* const zs  = smem;                   // [8][64] replicated z per wave
  float* const rdx = smem + 512;             // [8][64] bwd partials (cross-wave, B2)
  float* const cfs = smem + 1024;            // [8][64] coef transpose (wave-private)

  const int tid  = threadIdx.x;     // 0..511
  const int oid  = tid & 255;       // owned observation
  const int half = tid >> 8;        // bwd obs-slice half; A(0) writes shared state
  const int lane = tid & 63;
  const int w8   = tid >> 6;        // wave 0..7
  const int wsc  = w8 & 3;          // obs quarter (obs base wsc*64)
  const int t    = blockIdx.x;      // scenario

  const float delta = DLT[0];
  const float gamma = GMM[0];
  const float a     = fminf(delta * 0.5f, 255.0f / 256.0f);
  const float a256  = a * 256.0f;

  // ---- init: FULL residual row of owned obs (packed pairs); stage ep column-major (A) ----
  f32x2 er2[25];                                 // er2[p] = {er[2p], er[2p+1]}
  {
    float xr[NX];
    #pragma unroll
    for (int k = 0; k < NX; ++k) xr[k] = X[oid * NX + k];
    #pragma unroll
    for (int j = 0; j < NY; ++j) {               // W/B wave-uniform -> scalar loads
      float acc = Bb[j];
      #pragma unroll
      for (int k = 0; k < NX; ++k) acc = fmaf(xr[k], W[j * NX + k], acc);
      const float e = Y[oid * NY + j] - acc;
      if (j & 1) er2[j >> 1].y = e; else er2[j >> 1].x = e;   // static (unrolled)
      if (half == 0) smem[j * CSTR + oid] = e;
    }
    if (half == 0) smem[NY * CSTR + oid] = 1.0f; // ones column -> c gradient
  }
  float yhl;                                     // y_hat[t][lane] per-lane copy
  {
    const int jr = (lane < NY) ? lane : 0;
    float acc = Bb[jr];
    #pragma unroll
    for (int k = 0; k < NX; ++k) acc = fmaf(X[t * NX + k], W[jr * NX + k], acc);
    yhl = acc;
    if (tid < NY) out[NOBS * NY + t * NY + tid] = acc;
  }
  if (tid == 0) { th_key = 0xFFFFFFFFu; cctr[0] = 0; cctr[1] = 0; }
  if (tid < CAND) { ckey[0][tid] = 0xFFFFFFFFu; ckey[1][tid] = 0xFFFFFFFFu; }
  __syncthreads();

  // epb: iteration-invariant backward slice (packed pairs). Lane l: col min(l,50),
  // obs [wsc*64 + half*32, +32). coef of those obs -> cfs[w8*64 + half*32 + q].
  f32x2 epb2[16];
  {
    const int colc = (lane < 51) ? lane : 50;
    const float* eb = &smem[colc * CSTR + wsc * 64 + half * 32];
    #pragma unroll
    for (int q = 0; q < 8; ++q) {
      const float4 e4 = *(const float4*)&eb[4 * q];
      epb2[2*q]   = (f32x2){e4.x, e4.y};
      epb2[2*q+1] = (f32x2){e4.z, e4.w};
    }
  }
  __syncthreads();                               // ep_t dead -> overlays may be written

  float zv = (lane < NY) ? (1.0f / NY) : 0.0f;   // z one entry/lane, replicated per wave
  float cc = 0.0f;                               // c, replicated (bitwise identical)
  unsigned thk = 0xFFFFFFFFu;                    // loop-carried th_key copy (== LDS value)
  zs[w8 * 64 + lane] = zv;                       // wave-private z buffer (lanes>=50 -> 0)

  #pragma unroll 1
  for (int it = 0; it < NITER; ++it) {
    const int pp = it & 1;

    // ---- P0: fwd dot via wave-private LDS broadcast; packed FMA (25 pk ops) ----
    const float4* zp = (const float4*)&zs[w8 * 64];
    f32x2 a01 = {0.f, 0.f}, a23 = {0.f, 0.f};
    #pragma unroll
    for (int jq = 0; jq < 12; ++jq) {
      const float4 z4 = zp[jq];
      a01 = __builtin_elementwise_fma(er2[2*jq],   (f32x2){z4.x, z4.y}, a01);
      a23 = __builtin_elementwise_fma(er2[2*jq+1], (f32x2){z4.z, z4.w}, a23);
    }
    {
      const float4 z4 = zp[12];                  // z[48],z[49],0,0
      a01 = __builtin_elementwise_fma(er2[24], (f32x2){z4.x, z4.y}, a01);
    }
    const float u = ((a01.x + a23.x) + (a01.y + a23.y)) - cc;
    const float r = u * u;
    const unsigned key = __float_as_uint(r);     // non-negative f32 bits sort as u32

    float m = r;
    DPP_MAXSTEP(m, 0x111); DPP_MAXSTEP(m, 0x112);
    DPP_MAXSTEP(m, 0x114); DPP_MAXSTEP(m, 0x118);
    DPP_MAXSTEP(m, 0x142); DPP_MAXSTEP(m, 0x143);
    const float mw = rl_f(m, 63);                // wave (=quarter) max
    const int   wt = __popcll(__ballot(r == mw));

    const bool cond = (key <= thk);
    if (half == 0) {                             // A writes all shared state
      rrk[oid] = key;
      const unsigned long long cmask = __ballot(cond);
      const int cpos = __popcll(cmask & ((1ull << lane) - 1ull));
      const int cq   = __popcll(cmask);
      int base = 0;
      if (lane == 0) base = atomicAdd(&cctr[pp], cq);   // dense cross-quarter offset
      base = rl_i(base, 0);
      const int pos = base + cpos;               // slot order nondeterministic; cnt is
      if (cond && pos < 128) ckey[pp][pos] = key;//   order-independent -> deterministic
      if (lane == 0) { wmax4[wsc] = mw; wtie4[wsc] = wt; }
    }
    __syncthreads();                             // B1: ckey/cctr/stats/rrk

    // ---- P1: local rank scan (broadcast LDS loads); coef; bwd partials ----
    const int Cu = __builtin_amdgcn_readfirstlane(cctr[pp]);
    if (tid == 0) cctr[pp ^ 1] = 0;              // consumed last iter; next write 2 bar. away
    if (tid < CAND) ckey[pp ^ 1][tid] = 0xFFFFFFFFu;    // sentinel prefill for next iter

    const float4 wm  = *(const float4*)wmax4;
    const int4   wtv = *(const int4*)wtie4;
    const float mx = fmaxf(fmaxf(wm.x, wm.y), fmaxf(wm.z, wm.w));
    const int   cm = (wm.x == mx ? wtv.x : 0) + (wm.y == mx ? wtv.y : 0)
                   + (wm.z == mx ? wtv.z : 0) + (wm.w == mx ? wtv.w : 0);
    const bool ismax = (r == mx);
    const bool valid = ((float)Cu >= a256) && (Cu <= CAND);

    int cnt;
    if (__builtin_expect(valid, 1)) {
      // candidates (keys<=thk) downward-closed -> candidate rank == exact global rank;
      // non-candidates get cnt=C>=a256 -> gfac=1/256 (exact). Sentinels never count.
      const uint4* cp = (const uint4*)&ckey[pp][0];     // uniform addr -> broadcast reads
      int n0 = 0, n1 = 0, n2 = 0, n3 = 0;
      #pragma unroll
      for (int jq = 0; jq < CAND / 4; ++jq) {
        const uint4 k4 = cp[jq];
        n0 += (k4.x < key) ? 1 : 0;
        n1 += (k4.y < key) ? 1 : 0;
        n2 += (k4.z < key) ? 1 : 0;
        n3 += (k4.w < key) ? 1 : 0;
      }
      cnt = (n0 + n1) + (n2 + n3);
    } else {                                     // iter 0 / drift: exact full scan
      const uint4* p = (const uint4*)rrk;
      int n0 = 0, n1 = 0, n2 = 0, n3 = 0;
      #pragma unroll 4
      for (int jq = 0; jq < 64; ++jq) {
        const uint4 k4 = p[jq];
        n0 += (k4.x < key) ? 1 : 0;
        n1 += (k4.y < key) ? 1 : 0;
        n2 += (k4.z < key) ? 1 : 0;
        n3 += (k4.w < key) ? 1 : 0;
      }
      cnt = (n0 + n1) + (n2 + n3);
    }
    // rank-THRANK key refresh (unique when valid; dup writes of same value benign)
    if (cnt == THRANK && (!valid || cond)) th_key = key;

    const float gfac  = fminf(fmaxf((float)cnt + 1.0f - a256, 0.0f), 1.0f) * (1.0f / 256.0f);
    const float g     = gfac + (ismax ? (a / (float)cm) : 0.0f);
    const float coefv = 2.0f * u * g;

    // backward: coef transpose via wave-private LDS; packed FMA (16 pk ops)
    cfs[w8 * 64 + lane] = coefv;                 // in-order DS: reads below see this
    const float4* cfp = (const float4*)&cfs[w8 * 64 + half * 32];
    f32x2 qa = {0.f, 0.f}, qb = {0.f, 0.f};
    #pragma unroll
    for (int q = 0; q < 8; ++q) {
      const float4 c4 = cfp[q];                  // coef of obs wsc*64 + half*32 + 4q..+3
      qa = __builtin_elementwise_fma((f32x2){c4.x, c4.y}, epb2[2*q],   qa);
      qb = __builtin_elementwise_fma((f32x2){c4.z, c4.w}, epb2[2*q+1], qb);
    }
    rdx[w8 * 64 + lane] = (qa.x + qb.x) + (qa.y + qb.y);
    __syncthreads();                             // B2: rdx + th_key
    thk = th_key;                                // prefetch: final since P1; next write is
                                                 //   after next B1 -> WAR-safe
    // ---- P2: z/c gradient step; warm-started Michelot projection (0 LDS) ----
    const float r0 = rdx[lane],       r1 = rdx[64 + lane];
    const float r2 = rdx[128 + lane], r3 = rdx[192 + lane];
    const float r4 = rdx[256 + lane], r5 = rdx[320 + lane];
    const float r6 = rdx[384 + lane], r7 = rdx[448 + lane];
    const float s4 = ((r0 + r1) + (r2 + r3)) + ((r4 + r5) + (r6 + r7));
    cc = cc + LRATE * rl_f(s4, NY);              // gc = -sum(coef); lane 50 = ones column
    const float gz = s4 - gamma * yhl;
    const float v  = zv - LRATE * gz;            // column form: lane j holds v_j

    // Warm-start: seed support with carried {zv>0}; ballot-equality convergence is exact
    // (any fixed point (tau, A={v>tau}) with tau=(S_A-1)/|A| IS the projection).
    float tau = 0.0f;
    {
      bool cur = (lane < NY) && (zv > 0.0f);     // nonempty: sum(z)=1
      unsigned long long bal = __ballot(cur);
      int   n = __popcll(bal);
      float S = wave_sum_bcast(cur ? v : 0.0f);
      bool done = false;
      #pragma unroll 1
      for (int pass = 0; pass < 8; ++pass) {
        tau = (S - 1.0f) * __builtin_amdgcn_rcpf((float)n);
        const bool nxt = (lane < NY) && (v > tau);
        const unsigned long long nbal = __ballot(nxt);   // nonempty: max>mean>tau
        if (nbal == bal) { done = true; break; } // set equality -> fixed point (uniform)
        bal = nbal;
        n   = __popcll(nbal);
        S   = wave_sum_bcast(nxt ? v : 0.0f);
      }
      if (__builtin_expect(!done, 0)) {          // fallback: monotone shrink-from-full
        bool inm = (lane < NY);
        float Sf = wave_sum_bcast(inm ? v : 0.0f);
        int   nf = NY;
        #pragma unroll 1
        for (int pass = 0; pass < 32; ++pass) {
          tau = (Sf - 1.0f) * __builtin_amdgcn_rcpf((float)nf);
          const bool nin = inm && (v > tau);
          const int  nn  = __popcll(__ballot(nin));
          if (nn == nf) break;
          Sf = wave_sum_bcast(nin ? v : 0.0f);
          nf = nn;
          inm = nin;
        }
      }
    }
    zv = (lane < NY) ? fmaxf(v - tau, 0.0f) : 0.0f;
    zs[w8 * 64 + lane] = zv;                     // wave-private; next-iter P0 reads (in-order)
  }

  if (w8 == 0 && lane < NY) out[t * NY + lane] = zv;

}

extern "C" void kernel_launch(void* const* d_in, const int* in_sizes, int n_in,
                              void* d_out, int out_size, void* d_ws, size_t ws_size,
                              hipStream_t stream) {
  (void)in_sizes; (void)n_in; (void)d_ws; (void)ws_size; (void)out_size;
  const float* X   = (const float*)d_in[0];
  const float* Y   = (const float*)d_in[1];
  const float* W   = (const float*)d_in[2];
  const float* B   = (const float*)d_in[3];
  const float* DLT = (const float*)d_in[4];
  const float* GMM = (const float*)d_in[5];
  float* out = (float*)d_out;
  hipLaunchKernelGGL(dro_kernel, dim3(NOBS), dim3(512), 0, stream,
                     X, Y, W, B, DLT, GMM, out);
}

// Round 15
// 758.798 us; speedup vs baseline: 1.3080x; 1.0264x over previous
//
#include <hip/hip_runtime.h>
#include <cfloat>
#include <math.h>

#define NOBS   256
#define NY     50
#define NX     30
#define NITER  400
#define LRATE  0.05f
#define CSTR   260     // ep_t column stride (floats); %4==0 keeps float4 LDS loads 16B-aligned
#define THRANK 28      // theta tracks the rank-28 KEY -> C = 29 every valid iter (stable)
#define CAND   32      // candidate capacity: window [ceil(a256), 32], a256<=25.6 -> >=3 slack

typedef float f32x2 __attribute__((ext_vector_type(2)));

__device__ __forceinline__ float rl_f(float x, int k) {
  return __int_as_float(__builtin_amdgcn_readlane(__float_as_int(x), k));
}
__device__ __forceinline__ int rl_i(int x, int k) {
  return __builtin_amdgcn_readlane(x, k);
}

// wave64 max: row_shr 1,2,4,8 + row_bcast 15,31; old=x keeps unwritten lanes at identity.
#define DPP_MAXSTEP(x, ctrl)                                                       \
  x = fmaxf(x, __int_as_float(__builtin_amdgcn_update_dpp(                         \
        __float_as_int(x), __float_as_int(x), (ctrl), 0xF, 0xF, false)))

// wave64 SUM step: old=0 (NOT old=x -- sum is not idempotent; unfilled lanes must add 0).
#define DPP_SUMSTEP(x, ctrl, rmask)                                                \
  x += __int_as_float(__builtin_amdgcn_update_dpp(                                 \
        0, __float_as_int(x), (ctrl), (rmask), 0xF, false))

__device__ __forceinline__ float wave_sum_bcast(float x) {
  // full 64-lane sum, result broadcast to all lanes (readlane 63)
  DPP_SUMSTEP(x, 0x111, 0xF);   // row_shr:1
  DPP_SUMSTEP(x, 0x112, 0xF);   // row_shr:2
  DPP_SUMSTEP(x, 0x114, 0xF);   // row_shr:4
  DPP_SUMSTEP(x, 0x118, 0xF);   // row_shr:8  -> lanes 15/31/47/63 hold row sums
  DPP_SUMSTEP(x, 0x142, 0xA);   // row_bcast:15, rows 1,3 -> lanes 31/63 accumulate
  DPP_SUMSTEP(x, 0x143, 0xC);   // row_bcast:31, rows 2,3 -> lane 63 = total
  return rl_f(x, 63);
}

// R15 = R12/R14 (778us, 2x confirmed) + two chain cuts, values bitwise unchanged:
//  (1) P0 tail split across the replicated halves: half B (identical keys) does the
//      DPP-max/ties + wstat + rrk writes; half A does ONLY compaction (ballot ->
//      contended atomic ~65cyc [R13 calibration] -> scatter). Barrier arrival was half
//      A's full tail; now max of two shorter tails. Branches wave-uniform -> DPP safe.
//  (2) P1: 8 candidate loads issued SPECULATIVELY before the cctr->valid branch
//      (sentinel-prefilled buffer, always safe); prefill writes moved after. Overlaps
//      ~130cyc branch-resolution with load latency. [R11<->R12 calibration: each
//      uniform-b128 + 4 cmps on this chain ~ 75 cyc.]
// Chain-bound, not roofline-bound (VALU 44% / DS ~30% / HBM 0.01%). Tested-and-rejected:
// TLP (R10), 4-wave (R6), scan deletion (R11), LDS atomics for reduction (R13).
__global__ __launch_bounds__(512) __attribute__((amdgpu_waves_per_eu(2, 2)))
void dro_kernel(
    const float* __restrict__ X, const float* __restrict__ Y,
    const float* __restrict__ W, const float* __restrict__ Bb,
    const float* __restrict__ DLT, const float* __restrict__ GMM,
    float* __restrict__ out)
{
  __shared__ __align__(16) float smem[51 * CSTR];   // init: ep_t; after: overlays below
  __shared__ __align__(16) unsigned rrk[NOBS];      // full u32 keys (fallback scan)
  __shared__ __align__(16) unsigned ckey[2][128];   // parity-buffered dense candidates
  __shared__ __align__(16) float wmax4[4];
  __shared__ __align__(16) int   wtie4[4];
  __shared__ int cctr[2];                           // parity-buffered candidate counter
  __shared__ unsigned th_key;

  // Overlays (valid once ep_t is dead; disjoint; zs/cfs are WAVE-PRIVATE):
  float* const zs  = smem;                   // [8][64] replicated z per wave
  float* const rdx = smem + 512;             // [8][64] bwd partials (cross-wave, B2)
  float* const cfs = smem + 1024;            // [8][64] coef transpose (wave-private)

  const int tid  = threadIdx.x;     // 0..511
  const int oid  = tid & 255;       // owned observation
  const int half = tid >> 8;        // replicated halves; A(0)=compaction, B(1)=stats
  const int lane = tid & 63;
  const int w8   = tid >> 6;        // wave 0..7
  const int wsc  = w8 & 3;          // obs quarter (obs base wsc*64)
  const int t    = blockIdx.x;      // scenario

  const float delta = DLT[0];
  const float gamma = GMM[0];
  const float a     = fminf(delta * 0.5f, 255.0f / 256.0f);
  const float a256  = a * 256.0f;

  // ---- init: FULL residual row of owned obs (packed pairs); stage ep column-major (A) ----
  f32x2 er2[25];                                 // er2[p] = {er[2p], er[2p+1]}
  {
    float xr[NX];
    #pragma unroll
    for (int k = 0; k < NX; ++k) xr[k] = X[oid * NX + k];
    #pragma unroll
    for (int j = 0; j < NY; ++j) {               // W/B wave-uniform -> scalar loads
      float acc = Bb[j];
      #pragma unroll
      for (int k = 0; k < NX; ++k) acc = fmaf(xr[k], W[j * NX + k], acc);
      const float e = Y[oid * NY + j] - acc;
      if (j & 1) er2[j >> 1].y = e; else er2[j >> 1].x = e;   // static (unrolled)
      if (half == 0) smem[j * CSTR + oid] = e;
    }
    if (half == 0) smem[NY * CSTR + oid] = 1.0f; // ones column -> c gradient
  }
  float yhl;                                     // y_hat[t][lane] per-lane copy
  {
    const int jr = (lane < NY) ? lane : 0;
    float acc = Bb[jr];
    #pragma unroll
    for (int k = 0; k < NX; ++k) acc = fmaf(X[t * NX + k], W[jr * NX + k], acc);
    yhl = acc;
    if (tid < NY) out[NOBS * NY + t * NY + tid] = acc;
  }
  if (tid == 0) { th_key = 0xFFFFFFFFu; cctr[0] = 0; cctr[1] = 0; }
  if (tid < CAND) { ckey[0][tid] = 0xFFFFFFFFu; ckey[1][tid] = 0xFFFFFFFFu; }
  __syncthreads();

  // epb: iteration-invariant backward slice (packed pairs). Lane l: col min(l,50),
  // obs [wsc*64 + half*32, +32). coef of those obs -> cfs[w8*64 + half*32 + q].
  f32x2 epb2[16];
  {
    const int colc = (lane < 51) ? lane : 50;
    const float* eb = &smem[colc * CSTR + wsc * 64 + half * 32];
    #pragma unroll
    for (int q = 0; q < 8; ++q) {
      const float4 e4 = *(const float4*)&eb[4 * q];
      epb2[2*q]   = (f32x2){e4.x, e4.y};
      epb2[2*q+1] = (f32x2){e4.z, e4.w};
    }
  }
  __syncthreads();                               // ep_t dead -> overlays may be written

  float zv = (lane < NY) ? (1.0f / NY) : 0.0f;   // z one entry/lane, replicated per wave
  float cc = 0.0f;                               // c, replicated (bitwise identical)
  unsigned thk = 0xFFFFFFFFu;                    // loop-carried th_key copy (== LDS value)
  zs[w8 * 64 + lane] = zv;                       // wave-private z buffer (lanes>=50 -> 0)

  #pragma unroll 1
  for (int it = 0; it < NITER; ++it) {
    const int pp = it & 1;

    // ---- P0: fwd dot via wave-private LDS broadcast; packed FMA (25 pk ops) ----
    const float4* zp = (const float4*)&zs[w8 * 64];
    f32x2 a01 = {0.f, 0.f}, a23 = {0.f, 0.f};
    #pragma unroll
    for (int jq = 0; jq < 12; ++jq) {
      const float4 z4 = zp[jq];
      a01 = __builtin_elementwise_fma(er2[2*jq],   (f32x2){z4.x, z4.y}, a01);
      a23 = __builtin_elementwise_fma(er2[2*jq+1], (f32x2){z4.z, z4.w}, a23);
    }
    {
      const float4 z4 = zp[12];                  // z[48],z[49],0,0
      a01 = __builtin_elementwise_fma(er2[24], (f32x2){z4.x, z4.y}, a01);
    }
    const float u = ((a01.x + a23.x) + (a01.y + a23.y)) - cc;
    const float r = u * u;
    const unsigned key = __float_as_uint(r);     // non-negative f32 bits sort as u32

    const bool cond = (key <= thk);
    if (half == 1) {                             // B: stats + rrk (identical values to A's)
      rrk[oid] = key;
      float m = r;
      DPP_MAXSTEP(m, 0x111); DPP_MAXSTEP(m, 0x112);
      DPP_MAXSTEP(m, 0x114); DPP_MAXSTEP(m, 0x118);
      DPP_MAXSTEP(m, 0x142); DPP_MAXSTEP(m, 0x143);
      const float mw = rl_f(m, 63);              // wave (=quarter) max
      const int   wt = __popcll(__ballot(r == mw));
      if (lane == 0) { wmax4[wsc] = mw; wtie4[wsc] = wt; }
    } else {                                     // A: candidate compaction only
      const unsigned long long cmask = __ballot(cond);
      const int cpos = __popcll(cmask & ((1ull << lane) - 1ull));
      const int cq   = __popcll(cmask);
      int base = 0;
      if (lane == 0) base = atomicAdd(&cctr[pp], cq);   // dense cross-quarter offset
      base = rl_i(base, 0);
      const int pos = base + cpos;               // slot order nondeterministic; cnt is
      if (cond && pos < 128) ckey[pp][pos] = key;//   order-independent -> deterministic
    }
    __syncthreads();                             // B1: ckey/cctr/stats/rrk

    // ---- P1: speculative candidate loads; stats combine; rank; coef; bwd partials ----
    const uint4* cp = (const uint4*)&ckey[pp][0];       // uniform addr -> broadcast reads
    const uint4 k0_ = cp[0], k1_ = cp[1], k2_ = cp[2], k3_ = cp[3];   // issued before the
    const uint4 k4_ = cp[4], k5_ = cp[5], k6_ = cp[6], k7_ = cp[7];   //   valid branch
    const int Cu = __builtin_amdgcn_readfirstlane(cctr[pp]);
    const float4 wm  = *(const float4*)wmax4;
    const int4   wtv = *(const int4*)wtie4;
    if (tid == 0) cctr[pp ^ 1] = 0;              // consumed last iter; next write 2 bar. away
    if (tid < CAND) ckey[pp ^ 1][tid] = 0xFFFFFFFFu;    // sentinel prefill for next iter

    const float mx = fmaxf(fmaxf(wm.x, wm.y), fmaxf(wm.z, wm.w));
    const int   cm = (wm.x == mx ? wtv.x : 0) + (wm.y == mx ? wtv.y : 0)
                   + (wm.z == mx ? wtv.z : 0) + (wm.w == mx ? wtv.w : 0);
    const bool ismax = (r == mx);
    const bool valid = ((float)Cu >= a256) && (Cu <= CAND);

    int cnt;
    if (__builtin_expect(valid, 1)) {
      // candidates (keys<=thk) downward-closed -> candidate rank == exact global rank;
      // non-candidates get cnt=C>=a256 -> gfac=1/256 (exact). Sentinels never count.
      int n0 = 0, n1 = 0, n2 = 0, n3 = 0;
      n0 += (k0_.x < key) ? 1 : 0; n1 += (k0_.y < key) ? 1 : 0;
      n2 += (k0_.z < key) ? 1 : 0; n3 += (k0_.w < key) ? 1 : 0;
      n0 += (k1_.x < key) ? 1 : 0; n1 += (k1_.y < key) ? 1 : 0;
      n2 += (k1_.z < key) ? 1 : 0; n3 += (k1_.w < key) ? 1 : 0;
      n0 += (k2_.x < key) ? 1 : 0; n1 += (k2_.y < key) ? 1 : 0;
      n2 += (k2_.z < key) ? 1 : 0; n3 += (k2_.w < key) ? 1 : 0;
      n0 += (k3_.x < key) ? 1 : 0; n1 += (k3_.y < key) ? 1 : 0;
      n2 += (k3_.z < key) ? 1 : 0; n3 += (k3_.w < key) ? 1 : 0;
      n0 += (k4_.x < key) ? 1 : 0; n1 += (k4_.y < key) ? 1 : 0;
      n2 += (k4_.z < key) ? 1 : 0; n3 += (k4_.w < key) ? 1 : 0;
      n0 += (k5_.x < key) ? 1 : 0; n1 += (k5_.y < key) ? 1 : 0;
      n2 += (k5_.z < key) ? 1 : 0; n3 += (k5_.w < key) ? 1 : 0;
      n0 += (k6_.x < key) ? 1 : 0; n1 += (k6_.y < key) ? 1 : 0;
      n2 += (k6_.z < key) ? 1 : 0; n3 += (k6_.w < key) ? 1 : 0;
      n0 += (k7_.x < key) ? 1 : 0; n1 += (k7_.y < key) ? 1 : 0;
      n2 += (k7_.z < key) ? 1 : 0; n3 += (k7_.w < key) ? 1 : 0;
      cnt = (n0 + n1) + (n2 + n3);
    } else {                                     // iter 0 / drift: exact full scan
      const uint4* p = (const uint4*)rrk;
      int n0 = 0, n1 = 0, n2 = 0, n3 = 0;
      #pragma unroll 4
      for (int jq = 0; jq < 64; ++jq) {
        const uint4 k4 = p[jq];
        n0 += (k4.x < key) ? 1 : 0;
        n1 += (k4.y < key) ? 1 : 0;
        n2 += (k4.z < key) ? 1 : 0;
        n3 += (k4.w < key) ? 1 : 0;
      }
      cnt = (n0 + n1) + (n2 + n3);
    }
    // rank-THRANK key refresh (unique when valid; dup writes of same value benign)
    if (cnt == THRANK && (!valid || cond)) th_key = key;

    const float gfac  = fminf(fmaxf((float)cnt + 1.0f - a256, 0.0f), 1.0f) * (1.0f / 256.0f);
    const float g     = gfac + (ismax ? (a / (float)cm) : 0.0f);
    const float coefv = 2.0f * u * g;

    // backward: coef transpose via wave-private LDS; packed FMA (16 pk ops)
    cfs[w8 * 64 + lane] = coefv;                 // in-order DS: reads below see this
    const float4* cfp = (const float4*)&cfs[w8 * 64 + half * 32];
    f32x2 qa = {0.f, 0.f}, qb = {0.f, 0.f};
    #pragma unroll
    for (int q = 0; q < 8; ++q) {
      const float4 c4 = cfp[q];                  // coef of obs wsc*64 + half*32 + 4q..+3
      qa = __builtin_elementwise_fma((f32x2){c4.x, c4.y}, epb2[2*q],   qa);
      qb = __builtin_elementwise_fma((f32x2){c4.z, c4.w}, epb2[2*q+1], qb);
    }
    rdx[w8 * 64 + lane] = (qa.x + qb.x) + (qa.y + qb.y);
    __syncthreads();                             // B2: rdx + th_key
    thk = th_key;                                // prefetch: final since P1; next write is
                                                 //   after next B1 -> WAR-safe
    // ---- P2: z/c gradient step; warm-started Michelot projection (0 LDS) ----
    const float r0 = rdx[lane],       r1 = rdx[64 + lane];
    const float r2 = rdx[128 + lane], r3 = rdx[192 + lane];
    const float r4 = rdx[256 + lane], r5 = rdx[320 + lane];
    const float r6 = rdx[384 + lane], r7 = rdx[448 + lane];
    const float s4 = ((r0 + r1) + (r2 + r3)) + ((r4 + r5) + (r6 + r7));
    cc = cc + LRATE * rl_f(s4, NY);              // gc = -sum(coef); lane 50 = ones column
    const float gz = s4 - gamma * yhl;
    const float v  = zv - LRATE * gz;            // column form: lane j holds v_j

    // Warm-start: seed support with carried {zv>0}; ballot-equality convergence is exact
    // (any fixed point (tau, A={v>tau}) with tau=(S_A-1)/|A| IS the projection).
    float tau = 0.0f;
    {
      bool cur = (lane < NY) && (zv > 0.0f);     // nonempty: sum(z)=1
      unsigned long long bal = __ballot(cur);
      int   n = __popcll(bal);
      float S = wave_sum_bcast(cur ? v : 0.0f);
      bool done = false;
      #pragma unroll 1
      for (int pass = 0; pass < 8; ++pass) {
        tau = (S - 1.0f) * __builtin_amdgcn_rcpf((float)n);
        const bool nxt = (lane < NY) && (v > tau);
        const unsigned long long nbal = __ballot(nxt);   // nonempty: max>mean>tau
        if (nbal == bal) { done = true; break; } // set equality -> fixed point (uniform)
        bal = nbal;
        n   = __popcll(nbal);
        S   = wave_sum_bcast(nxt ? v : 0.0f);
      }
      if (__builtin_expect(!done, 0)) {          // fallback: monotone shrink-from-full
        bool inm = (lane < NY);
        float Sf = wave_sum_bcast(inm ? v : 0.0f);
        int   nf = NY;
        #pragma unroll 1
        for (int pass = 0; pass < 32; ++pass) {
          tau = (Sf - 1.0f) * __builtin_amdgcn_rcpf((float)nf);
          const bool nin = inm && (v > tau);
          const int  nn  = __popcll(__ballot(nin));
          if (nn == nf) break;
          Sf = wave_sum_bcast(nin ? v : 0.0f);
          nf = nn;
          inm = nin;
        }
      }
    }
    zv = (lane < NY) ? fmaxf(v - tau, 0.0f) : 0.0f;
    zs[w8 * 64 + lane] = zv;                     // wave-private; next-iter P0 reads (in-order)
  }

  if (w8 == 0 && lane < NY) out[t * NY + lane] = zv;

}

extern "C" void kernel_launch(void* const* d_in, const int* in_sizes, int n_in,
                              void* d_out, int out_size, void* d_ws, size_t ws_size,
                              hipStream_t stream) {
  (void)in_sizes; (void)n_in; (void)d_ws; (void)ws_size; (void)out_size;
  const float* X   = (const float*)d_in[0];
  const float* Y   = (const float*)d_in[1];
  const float* W   = (const float*)d_in[2];
  const float* B   = (const float*)d_in[3];
  const float* DLT = (const float*)d_in[4];
  const float* GMM = (const float*)d_in[5];
  float* out = (float*)d_out;
  hipLaunchKernelGGL(dro_kernel, dim3(NOBS), dim3(512), 0, stream,
                     X, Y, W, B, DLT, GMM, out);
}